// Round 8
// baseline (224.885 us; speedup 1.0000x reference)
//
#include <hip/hip_runtime.h>
#include <hip/hip_fp16.h>

// CTC forward loss. B=64, T=2000, C=128 (blank=127), Lmax=200, S=401.
// SINGLE kernel, intra-block producer-consumer. One block per batch (256 thr).
// v8 = v7 + manually-scheduled consumer LDS pipeline:
//   v6/v7 established the consumer is STALL-bound, not issue-bound (removing
//   16% of round2's instructions gave 0.8%). Remaining suspect with the right
//   magnitude (~250 cyc/round2): compiler-emitted conservative s_waitcnt
//   lgkmcnt around the per-iteration ds_read prefetches. v8 issues the
//   consumer's chunk reads via inline-asm ds_read_b128/b64 into 3 rotating
//   NAMED register sets (prefetch distance 2 pairs), with explicit counted
//   s_waitcnt lgkmcnt(6) (two younger triples in flight) + sched_barrier(0)
//   after each wait (rule #18), lgkmcnt(3)/(0) at chunk tail. The compiler
//   can't see the asm loads so it inserts no waits of its own. Consumer wave
//   also runs at s_setprio(1) (LDS-pipe arbitration vs producer bursts).
//   wave 0      : alpha recursion (linear domain + pow2 exponent tracking,
//                 DPP halos, 8 states/lane). f32 quad LDS format (v7).
//   waves 1..3  : producers (v7): pair-granular, branch-free, 4-bpermute
//                 half2 gather + producer-side cvt to f32, 2x ds_write_b128.
// Sync: one __syncthreads() per chunk; double buffer parity k&1; garbage
// pairs -> scratch slots 16/17 or clamped rows, never read by the consumer.

#define LOG2E 1.44269504088896340736f
#define LN2F  0.69314718055994530942f

namespace {

constexpr int Bc = 64, Tc = 2000, Cc = 128, Lmaxc = 200;
constexpr int PAIRB = 2048;                  // bytes per pair (2 x 1KB quads)
constexpr int CHP = 16;                      // pairs per chunk (32 steps)
constexpr int CHPA = 18;                     // allocated pair slots (2 scratch)
constexpr int CHB = CHPA * PAIRB;            // 36 KB per buffer

typedef __attribute__((address_space(3))) void* las_ptr;
using u32x4 = __attribute__((ext_vector_type(4))) unsigned;
using f32x2 = __attribute__((ext_vector_type(2))) float;

__device__ __forceinline__ float dpp_shr1_f(float x) {  // lane i <- i-1, lane0 <- 0
  return __int_as_float(
      __builtin_amdgcn_update_dpp(0, __float_as_int(x), 0x138, 0xF, 0xF, true));
}
__device__ __forceinline__ float dpp_shl1_f(float x) {  // lane i <- i+1, lane63 <- 0
  return __int_as_float(
      __builtin_amdgcn_update_dpp(0, __float_as_int(x), 0x130, 0xF, 0xF, true));
}
__device__ __forceinline__ int dpp_shr1_i(int x) {
  return __builtin_amdgcn_update_dpp(0, x, 0x138, 0xF, 0xF, true);
}
template <int CTRL>
__device__ __forceinline__ float dpp_add(float v) {
  return v + __int_as_float(
      __builtin_amdgcn_update_dpp(0, __float_as_int(v), CTRL, 0xF, 0xF, true));
}
__device__ __forceinline__ float wave_sum_bcast(float v) {  // full-wave sum
  v = dpp_add<0x111>(v);
  v = dpp_add<0x112>(v);
  v = dpp_add<0x114>(v);
  v = dpp_add<0x118>(v);
  v = dpp_add<0x142>(v);
  v = dpp_add<0x143>(v);
  return __int_as_float(__builtin_amdgcn_readlane(__float_as_int(v), 63));
}
__device__ __forceinline__ float h16_to_f32(unsigned h) {
  __half_raw hr;
  hr.x = (unsigned short)h;
  return __half2float(__half(hr));
}

__global__ __launch_bounds__(256, 1) void ctc_fused_kernel(
    const float* __restrict__ y, const int* __restrict__ y_true,
    const int* __restrict__ in_len, const int* __restrict__ lab_len,
    float* __restrict__ out) {
  __shared__ __align__(16) char bufs[2][CHB];   // 72 KB pair double buffer
  __shared__ __align__(16) float blkb[2][40];   // blank probs (+scratch tail)

  const int b = blockIdx.x;
  const int wv = threadIdx.x >> 6, lane = threadIdx.x & 63;
  const int lane16 = lane * 16;

  int len = in_len[b];
  len = len < 1 ? 1 : (len > Tc ? Tc : len);
  const int R = (len - 1) >> 1;          // full pair-rounds
  const int leftover = (len - 1) & 1;
  const int PRtot = R + leftover;        // pairs touched
  const int NCg = (PRtot + CHP - 1) / CHP;
  const int cfull = R / CHP;
  const int* labs = y_true + b * Lmaxc;

  // ---- producer-side label classes (pack_kernel's fix() semantics) ----
  int pbase = 4 * lane;
  if (pbase > Lmaxc - 4) pbase = Lmaxc - 4;
  const int4 Lw = *(const int4*)(labs + pbase);
  auto fix = [&](int v, int idx) {
    int r = (idx > Lmaxc - 1) ? Lw.w : v;  // idx>199 -> labs[199]
    return r < 0 ? 0 : r;                  // padded -1 -> 0
  };
  const int c0 = fix(Lw.x, 4 * lane), c1 = fix(Lw.y, 4 * lane + 1);
  const int c2 = fix(Lw.z, 4 * lane + 2), c3 = fix(Lw.w, 4 * lane + 3);
  const float* yrow = y + (size_t)b * Tc * Cc + 2 * lane;

  // softmax + half2-gather (4 bpermutes, proven v4 path) -> 4 f32 label probs
  auto pack2f = [&](float2 yy, float& bl) -> uint4 {
    float e0 = exp2f(fminf(yy.x * LOG2E, 50.f));
    float e1 = exp2f(fminf(yy.y * LOG2E, 50.f));
    const float rs = 1.0f / wave_sum_bcast(e0 + e1);
    unsigned q2 =
        __builtin_bit_cast(unsigned, __floats2half2_rn(e0 * rs, e1 * rs));
    unsigned g0 = (unsigned)__builtin_amdgcn_ds_bpermute((c0 >> 1) << 2, (int)q2);
    unsigned g1 = (unsigned)__builtin_amdgcn_ds_bpermute((c1 >> 1) << 2, (int)q2);
    unsigned g2 = (unsigned)__builtin_amdgcn_ds_bpermute((c2 >> 1) << 2, (int)q2);
    unsigned g3 = (unsigned)__builtin_amdgcn_ds_bpermute((c3 >> 1) << 2, (int)q2);
    unsigned h0 = (c0 & 1) ? (g0 >> 16) : (g0 & 0xFFFFu);
    unsigned h1 = (c1 & 1) ? (g1 >> 16) : (g1 & 0xFFFFu);
    unsigned h2 = (c2 & 1) ? (g2 >> 16) : (g2 & 0xFFFFu);
    unsigned h3 = (c3 & 1) ? (g3 >> 16) : (g3 & 0xFFFFu);
    bl = e1 * rs;  // lane 63 holds class-127 (blank) prob
    return make_uint4(__builtin_bit_cast(unsigned, h16_to_f32(h0)),
                      __builtin_bit_cast(unsigned, h16_to_f32(h1)),
                      __builtin_bit_cast(unsigned, h16_to_f32(h2)),
                      __builtin_bit_cast(unsigned, h16_to_f32(h3)));
  };

  // producer: wave wv packs local pairs wv-1 + 3i (i<6) of chunk kp.
  auto produce = [&](int kp) {
    char* pbuf = &bufs[kp & 1][0];
    float* bb = blkb[kp & 1];
    const int pq0 = wv - 1;              // 0,1,2
    const int tbase = 32 * kp + 1;       // step of slot A of local pair 0
    // ---- stage 1: all 12 row loads in flight (named regs only) ----
    float2 yA0, yB0, yA1, yB1, yA2, yB2, yA3, yB3, yA4, yB4, yA5, yB5;
#define LOADP(i, yA, yB)                                    \
  {                                                         \
    int tA = tbase + 2 * (pq0 + 3 * (i));                   \
    int tB = tA + 1;                                        \
    tA = tA > Tc - 1 ? Tc - 1 : tA;                         \
    tB = tB > Tc - 1 ? Tc - 1 : tB;                         \
    yA = *(const float2*)(yrow + (size_t)tA * Cc);          \
    yB = *(const float2*)(yrow + (size_t)tB * Cc);          \
  }
    LOADP(0, yA0, yB0)
    LOADP(1, yA1, yB1)
    LOADP(2, yA2, yB2)
    LOADP(3, yA3, yB3)
    LOADP(4, yA4, yB4)
    LOADP(5, yA5, yB5)
#undef LOADP
    // ---- stage 2: compute + write 6 pairs, straight-line ----
#define PACKP(i, yA, yB)                                             \
  {                                                                  \
    const int pq = pq0 + 3 * (i);                                    \
    float blA, blB;                                                  \
    const uint4 wA = pack2f(yA, blA);                                \
    const uint4 wB = pack2f(yB, blB);                                \
    *(uint4*)(pbuf + pq * PAIRB + lane16) = wA;                      \
    *(uint4*)(pbuf + pq * PAIRB + 1024 + lane16) = wB;               \
    if (lane == 63) *(float2*)(bb + 2 * pq) = make_float2(blA, blB); \
  }
    PACKP(0, yA0, yB0)
    PACKP(1, yA1, yB1)
    PACKP(2, yA2, yB2)
    PACKP(3, yA3, yB3)
    PACKP(4, yA4, yB4)
    PACKP(5, yA5, yB5)
#undef PACKP
  };

  // ---- consumer-side per-lane state (wave 0 only uses it) ----
  const int ll = lab_len[b];
  auto labc = [&](int l) -> int {
    int lc = l < 0 ? 0 : (l > Lmaxc - 1 ? Lmaxc - 1 : l);
    int c = labs[lc];
    return c < 0 ? 0 : c;
  };
  const int c0i = labc(4 * lane), c1i = labc(4 * lane + 1);
  const int c2i = labc(4 * lane + 2), c3i = labc(4 * lane + 3);
  const int cm1 = labc(4 * lane - 1), cm2 = labc(4 * lane - 2);
  const float sk0 = (4 * lane >= 1 && c0i != cm1) ? 1.f : 0.f;
  const float sk1 = (c1i != c0i) ? 1.f : 0.f;
  const float sk2 = (c2i != c1i) ? 1.f : 0.f;
  const float sk3 = (c3i != c2i) ? 1.f : 0.f;
  const float skH = (lane >= 1 && cm1 != cm2) ? 1.f : 0.f;
  const float skHn = dpp_shl1_f(skH);  // skH of lane+1 (const, hoisted)

  float a0 = 0.f, a1 = 0.f, a2 = 0.f, a3 = 0.f;
  float a4 = 0.f, a5 = 0.f, a6 = 0.f, a7 = 0.f;
  int E = 0;
  if (wv == 0) {  // seed from y row t=0 (row 0 is never packed)
    const float* y0 = y + (size_t)b * Tc * Cc + 2 * lane;
    float e0 = exp2f(fminf(y0[0] * LOG2E, 50.f));
    float e1 = exp2f(fminf(y0[1] * LOG2E, 50.f));
    const float rs = 1.0f / wave_sum_bcast(e0 + e1);
    int l0 = labs[0];
    l0 = l0 < 0 ? 0 : l0;
    float ev = (l0 & 1) ? e1 : e0;
    float q0 = __int_as_float(__builtin_amdgcn_readlane(__float_as_int(ev), l0 >> 1)) * rs;
    float qb = __int_as_float(__builtin_amdgcn_readlane(__float_as_int(e1), 63)) * rs;
    if (lane == 0) { a0 = qb; a1 = q0; }
  }
  float s7d = dpp_shr1_f(a7);
  float zsd = dpp_shr1_f(fmaf(skHn, a5, a6));  // s6d + skH*s5d, one dpp
  int epd = 0;
  float corr = (lane == 0) ? 0.f : 1.f;

  // pair-round: 2 lattice steps from two f32 quads + f32 blank pair
  auto round2 = [&](u32x4 qa, u32x4 qb, f32x2 bl, bool renorm) {
    const float pA0 = __uint_as_float(qa.x), pA1 = __uint_as_float(qa.y);
    const float pA2 = __uint_as_float(qa.z), pA3 = __uint_as_float(qa.w);
    const float pB0 = __uint_as_float(qb.x), pB1 = __uint_as_float(qb.y);
    const float pB2 = __uint_as_float(qb.z), pB3 = __uint_as_float(qb.w);
    const float qbA = bl.x, qbB = bl.y;
    const float qhA = dpp_shr1_f(pA3);    // halo label prob (VALU pipe)
    const float w7 = s7d * corr;
    const float hA = fmaf(corr, zsd, w7) * qhA;  // == (w7+w6+skH*w5)*qhA
    float n0 = (a0 + w7) * qbA;
    float n1 = (a1 + a0 + sk0 * w7) * pA0;
    float n2 = (a2 + a1) * qbA;
    float n3 = (a3 + a2 + sk1 * a1) * pA1;
    float n4 = (a4 + a3) * qbA;
    float n5 = (a5 + a4 + sk2 * a3) * pA2;
    float n6 = (a6 + a5) * qbA;
    float n7 = (a7 + a6 + sk3 * a5) * pA3;
    a0 = (n0 + hA) * qbB;
    a1 = (n1 + n0 + sk0 * hA) * pB0;
    a2 = (n2 + n1) * qbB;
    a3 = (n3 + n2 + sk1 * n1) * pB1;
    a4 = (n4 + n3) * qbB;
    a5 = (n5 + n4 + sk2 * n3) * pB2;
    a6 = (n6 + n5) * qbB;
    a7 = (n7 + n6 + sk3 * n5) * pB3;
    if (renorm) {  // every 8 steps, exact pow2
      float mx = fmaxf(fmaxf(fmaxf(a0, a1), fmaxf(a2, a3)),
                       fmaxf(fmaxf(a4, a5), fmaxf(a6, a7)));
      unsigned bits = __float_as_uint(mx);
      bool z = (bits == 0u);
      int e = (int)(bits >> 23) - 127;
      float f = __uint_as_float((254u - (bits >> 23)) << 23);  // 2^-e
      f = z ? 1.0f : f;
      a0 *= f; a1 *= f; a2 *= f; a3 *= f;
      a4 *= f; a5 *= f; a6 *= f; a7 *= f;
      E = z ? epd : (E + e);
    }
    s7d = dpp_shr1_f(a7);
    zsd = dpp_shr1_f(fmaf(skHn, a5, a6));
    if (renorm) {
      epd = dpp_shr1_i(E);
      int de = epd - E;
      de = de < -126 ? -126 : (de > 60 ? 60 : de);
      corr = __int_as_float((de + 127) << 23);
      corr = (lane == 0) ? 0.0f : corr;
    }
  };

  // consume one full 16-pair chunk: inline-asm ds_reads into 3 rotating
  // named register sets, counted lgkmcnt waits, sched_barrier fences.
  auto consume = [&](int k) {
    const unsigned cbase =
        (unsigned)(uintptr_t)(las_ptr)(&bufs[k & 1][0]) + (unsigned)lane16;
    const unsigned bbase = (unsigned)(uintptr_t)(las_ptr)(&blkb[k & 1][0]);
    u32x4 A0, B0, A1, B1, A2, B2;
    f32x2 L0, L1, L2;
#define ISSUE(Sa, Sb, Sl, p)                                              \
  {                                                                       \
    unsigned aA = cbase + (unsigned)((p) * 2048);                         \
    asm volatile("ds_read_b128 %0, %1" : "=v"(Sa) : "v"(aA));             \
    asm volatile("ds_read_b128 %0, %1 offset:1024" : "=v"(Sb) : "v"(aA)); \
    unsigned aL = bbase + (unsigned)((p) * 8);                            \
    asm volatile("ds_read_b64 %0, %1" : "=v"(Sl) : "v"(aL));              \
  }
#define WAITSB(n)                              \
  asm volatile("s_waitcnt lgkmcnt(" #n ")");   \
  __builtin_amdgcn_sched_barrier(0);
    ISSUE(A0, B0, L0, 0)
    ISSUE(A1, B1, L1, 1)
    ISSUE(A2, B2, L2, 2)  WAITSB(6) round2(A0, B0, L0, false);   // p=0
    ISSUE(A0, B0, L0, 3)  WAITSB(6) round2(A1, B1, L1, false);   // p=1
    ISSUE(A1, B1, L1, 4)  WAITSB(6) round2(A2, B2, L2, false);   // p=2
    ISSUE(A2, B2, L2, 5)  WAITSB(6) round2(A0, B0, L0, true);    // p=3
    ISSUE(A0, B0, L0, 6)  WAITSB(6) round2(A1, B1, L1, false);   // p=4
    ISSUE(A1, B1, L1, 7)  WAITSB(6) round2(A2, B2, L2, false);   // p=5
    ISSUE(A2, B2, L2, 8)  WAITSB(6) round2(A0, B0, L0, false);   // p=6
    ISSUE(A0, B0, L0, 9)  WAITSB(6) round2(A1, B1, L1, true);    // p=7
    ISSUE(A1, B1, L1, 10) WAITSB(6) round2(A2, B2, L2, false);   // p=8
    ISSUE(A2, B2, L2, 11) WAITSB(6) round2(A0, B0, L0, false);   // p=9
    ISSUE(A0, B0, L0, 12) WAITSB(6) round2(A1, B1, L1, false);   // p=10
    ISSUE(A1, B1, L1, 13) WAITSB(6) round2(A2, B2, L2, true);    // p=11
    ISSUE(A2, B2, L2, 14) WAITSB(6) round2(A0, B0, L0, false);   // p=12
    ISSUE(A0, B0, L0, 15) WAITSB(6) round2(A1, B1, L1, false);   // p=13
    WAITSB(3) round2(A2, B2, L2, false);                         // p=14
    WAITSB(0) round2(A0, B0, L0, true);                          // p=15
#undef ISSUE
#undef WAITSB
  };

  // ---- pipeline: uniform barriers, producers one chunk ahead ----
  if (wv == 0) __builtin_amdgcn_s_setprio(1);
  if (wv != 0 && NCg > 0) produce(0);
  __syncthreads();
  for (int k = 0; k < cfull; ++k) {
    if (wv == 0) {
      consume(k);
    } else if (k + 1 < NCg) {
      produce(k + 1);
    }
    __syncthreads();
  }

  if (wv != 0) return;  // producers done (no barriers past this point)

  // tail: remaining pair-rounds + optional single step, from tail chunk
  {
    const char* tb = &bufs[cfull & 1][0];
    const float* pbT = blkb[cfull & 1];
    const int rem = R - cfull * CHP;
    for (int r = 0; r < rem; ++r) {
      u32x4 qa = *(const u32x4*)(tb + r * PAIRB + lane16);
      u32x4 qb2 = *(const u32x4*)(tb + r * PAIRB + 1024 + lane16);
      f32x2 bl = *(const f32x2*)(pbT + 2 * r);
      round2(qa, qb2, bl, (r & 3) == 3);
    }
    if (leftover) {  // final odd step: slot A of pair R
      u32x4 qa = *(const u32x4*)(tb + rem * PAIRB + lane16);
      float blA = *(pbT + 2 * rem);
      const float pA0 = __uint_as_float(qa.x), pA1 = __uint_as_float(qa.y);
      const float pA2 = __uint_as_float(qa.z), pA3 = __uint_as_float(qa.w);
      float s7 = dpp_shr1_f(a7);
      int ep = dpp_shr1_i(E);
      int de = ep - E;
      de = de < -126 ? -126 : (de > 60 ? 60 : de);
      float c2v = __int_as_float((de + 127) << 23);
      c2v = (lane == 0) ? 0.0f : c2v;
      float w7 = s7 * c2v;
      float n0 = (a0 + w7) * blA;
      float n1 = (a1 + a0 + sk0 * w7) * pA0;
      float n2 = (a2 + a1) * blA;
      float n3 = (a3 + a2 + sk1 * a1) * pA1;
      float n4 = (a4 + a3) * blA;
      float n5 = (a5 + a4 + sk2 * a3) * pA2;
      float n6 = (a6 + a5) * blA;
      float n7 = (a7 + a6 + sk3 * a5) * pA3;
      a0 = n0; a1 = n1; a2 = n2; a3 = n3;
      a4 = n4; a5 = n5; a6 = n6; a7 = n7;
    }
  }

  // final combine: loss = -lse(alpha[2ll], alpha[2ll-1]) in log2 domain
  int sE = 2 * ll;
  int sP = sE - 1 < 0 ? 0 : sE - 1;
  int laneA = sE >> 3, jA = sE & 7;
  int laneB = sP >> 3, jB = sP & 7;
  float va = a0;
  if (jA == 1) va = a1;
  if (jA == 2) va = a2;
  if (jA == 3) va = a3;
  if (jA == 4) va = a4;
  if (jA == 5) va = a5;
  if (jA == 6) va = a6;
  if (jA == 7) va = a7;
  float vb = a0;
  if (jB == 1) vb = a1;
  if (jB == 2) vb = a2;
  if (jB == 3) vb = a3;
  if (jB == 4) vb = a4;
  if (jB == 5) vb = a5;
  if (jB == 6) vb = a6;
  if (jB == 7) vb = a7;
  float aA = __int_as_float(__builtin_amdgcn_ds_bpermute(laneA << 2, __float_as_int(va)));
  float aB = __int_as_float(__builtin_amdgcn_ds_bpermute(laneB << 2, __float_as_int(vb)));
  int EA = __builtin_amdgcn_ds_bpermute(laneA << 2, E);
  int EB = __builtin_amdgcn_ds_bpermute(laneB << 2, E);
  if (lane == 0) {
    float l1 = (aA > 0.0f) ? (float)EA + log2f(aA) : -1e30f;
    float l2 = (aB > 0.0f) ? (float)EB + log2f(aB) : -1e30f;
    float mm = fmaxf(l1, l2);
    float v = mm + log2f(exp2f(l1 - mm) + exp2f(l2 - mm));
    out[b] = -v * LN2F;
  }
}

}  // namespace

extern "C" void kernel_launch(void* const* d_in, const int* in_sizes, int n_in,
                              void* d_out, int out_size, void* d_ws, size_t ws_size,
                              hipStream_t stream) {
  const float* y = (const float*)d_in[0];   // [64,2000,128] f32
  const int* yt = (const int*)d_in[1];      // [64,200] i32
  const int* il = (const int*)d_in[2];      // [64] i32
  const int* lb = (const int*)d_in[3];      // [64] i32
  float* out = (float*)d_out;               // [64] f32
  (void)d_ws; (void)ws_size;                // no workspace needed

  hipLaunchKernelGGL(ctc_fused_kernel, dim3(Bc), dim3(256), 0, stream,
                     y, yt, il, lb, out);
}